// Round 9
// baseline (95.751 us; speedup 1.0000x reference)
//
#include <hip/hip_runtime.h>
#include <cstdint>

// B=4, N=256, D=128, HID=128, IN_DIM=516.
// G[i,j,h] = [|hi-hj| ; hi*hj] @ W1[256:512]  (K=256 fp8 MFMA, W x256) -- symmetric in (i,j)
// pre' = 256*pre = acc + PiB'[i,h] + Pjf'[j,h] + scal'(i,j)·w   (all pre-scaled x256)
// L = relu(pre') @ (W2/256) + b2 ; out[i,j]=out[j,i]=0.5*(L_f+L_m) ; diag -1e9.
// R9 = R8 + DPP quad reduction (no ds_swizzle), fp32 sScal (no unpack), batched pre_k.

typedef float f32x4 __attribute__((ext_vector_type(4)));

#define INV256 0.00390625f

__device__ __forceinline__ uint32_t pk4(float a, float b, float c, float d) {
  uint32_t u = __builtin_amdgcn_cvt_pk_fp8_f32(a, b, 0, false);
  u = __builtin_amdgcn_cvt_pk_fp8_f32(c, d, u, true);
  return u;
}
__device__ __forceinline__ uint32_t pkbf2(float lo, float hi) {
  uint32_t l = __builtin_bit_cast(uint32_t, lo);
  uint32_t h = __builtin_bit_cast(uint32_t, hi);
  return (l >> 16) | (h & 0xffff0000u);
}
__device__ __forceinline__ float ulo(uint32_t u) {
  return __builtin_bit_cast(float, u << 16);
}
__device__ __forceinline__ float uhi(uint32_t u) {
  return __builtin_bit_cast(float, u & 0xffff0000u);
}
__device__ __forceinline__ long mk64(uint32_t lo, uint32_t hi) {
  return (long)((((unsigned long long)hi) << 32) | lo);
}
// butterfly sum over lane-groups of 4 (quad_perm DPP, pure VALU -- no LDS)
__device__ __forceinline__ float qsum4(float v) {
  v += __builtin_bit_cast(float, __builtin_amdgcn_update_dpp(
           0, __builtin_bit_cast(int, v), 0xB1, 0xF, 0xF, true));  // xor 1
  v += __builtin_bit_cast(float, __builtin_amdgcn_update_dpp(
           0, __builtin_bit_cast(int, v), 0x4E, 0xF, 0xF, true));  // xor 2
  return v;
}

// bid<32 (tid<128): pack fp8 B-image (lane-linear MFMA fragment order, W x256)
// bid in [32,288): 4 rows/block: PiB' = 256*(node@W1[0:128] + b1); Pjf' = 256*(node@W1[128:256])
__global__ __launch_bounds__(256) void pre_k(const float* __restrict__ node,
                                             const float* __restrict__ W1,
                                             const float* __restrict__ b1,
                                             float* __restrict__ PiB,
                                             float* __restrict__ Pjf,
                                             uint32_t* __restrict__ W1f8) {
  int bid = blockIdx.x;
  int tid = threadIdx.x;
  if (bid < 32) {
    if (tid < 128) {
      int ks = bid >> 2, nip = (bid >> 1) & 1, wn = bid & 1;
      int lane = tid & 63, nilow = tid >> 6;
      int quad = lane >> 4, col = lane & 15;
      int h = wn * 64 + (nip * 2 + nilow) * 16 + col;
      int k0 = ks * 32 + quad * 8;
      float w[8];
#pragma unroll
      for (int t = 0; t < 8; ++t) w[t] = W1[(256 + k0 + t) * 128 + h] * 256.0f;
      uint2 u;
      u.x = pk4(w[0], w[1], w[2], w[3]);
      u.y = pk4(w[4], w[5], w[6], w[7]);
      reinterpret_cast<uint2*>(W1f8)[(bid * 64 + lane) * 2 + nilow] = u;
    }
    return;
  }
  __shared__ float sN[512];  // [d][r] transposed, 128 x 4
  const int r0 = (bid - 32) * 4;
  {
    int d = tid & 127, rh = tid >> 7;
#pragma unroll
    for (int rr = 0; rr < 2; ++rr) {
      int row = rr * 2 + rh;
      sN[d * 4 + row] = node[(size_t)(r0 + row) * 128 + d];
    }
  }
  __syncthreads();
  const int h = tid & 127, proj = tid >> 7;
  const float* Wp = W1 + (size_t)proj * 128 * 128 + h;
  float a0 = 0.f, a1 = 0.f, a2 = 0.f, a3 = 0.f;
#pragma unroll 4
  for (int d = 0; d < 128; ++d) {
    float w = Wp[(size_t)d * 128];
    float4 v = *reinterpret_cast<const float4*>(&sN[d * 4]);
    a0 = fmaf(v.x, w, a0);
    a1 = fmaf(v.y, w, a1);
    a2 = fmaf(v.z, w, a2);
    a3 = fmaf(v.w, w, a3);
  }
  float bb = (proj == 0) ? b1[h] : 0.f;
  float* dst = (proj == 0) ? PiB : Pjf;
  dst[(size_t)(r0 + 0) * 128 + h] = 256.f * (a0 + bb);
  dst[(size_t)(r0 + 1) * 128 + h] = 256.f * (a1 + bb);
  dst[(size_t)(r0 + 2) * 128 + h] = 256.f * (a2 + bb);
  dst[(size_t)(r0 + 3) * 128 + h] = 256.f * (a3 + bb);
}

// grid 2112 = b(4) * 528 unordered 8-group pairs (I<=J). 64 pairs/block, K=256 fp8.
// waves: wn2 = tid>>6 owns h-cols [wn2*32, wn2*32+32) (ni tiles 2wn2, 2wn2+1).
__global__ __launch_bounds__(256, 5) void main_k(
    const float* __restrict__ node, const float* __restrict__ baseL,
    const float* __restrict__ compL, const float* __restrict__ W1,
    const float* __restrict__ W2, const float* __restrict__ b2,
    const uint32_t* __restrict__ W1f8, const float* __restrict__ PiB,
    const float* __restrict__ Pjf, float* __restrict__ out) {
  // sF: [ks 0..7][mi 0..3][q 0..3][scol 0..15] 8B, scol=(col+2q+4(ks&3))&15 -> 16384 B
  //   overlaid post-MFMA by sP: [64 pairs][42] fp32 (fwd partials @0..15, mirror @20..35)
  // sPP: [16 rows][132] u32 {bf16 PiB' | bf16 Pjf'} (rows 0-7 I-group, 8-15 J-group)
  // sScal: [64 pairs][12] fp32: fwd {bl',sg',cl',sg'} @0, mirror @4 (stride 12: bank-clean)
  __shared__ __align__(16) char smem[16384];
  __shared__ __align__(16) uint32_t sPP[16 * 132];
  __shared__ __align__(16) float sScal[64 * 12];
  char* sF = smem;
  float* sP = reinterpret_cast<float*>(smem);  // overlay

  const int tid = threadIdx.x;
  const int bx = blockIdx.x;
  const int b = bx / 528;
  const int t = bx - b * 528;
  int tI = (int)((65.0f - sqrtf(4225.0f - 8.0f * (float)t)) * 0.5f);
  tI = (tI < 0) ? 0 : (tI > 31 ? 31 : tI);
  while (((65 * tI - tI * tI) >> 1) > t) --tI;
  while (tI < 31 && ((65 * (tI + 1) - (tI + 1) * (tI + 1)) >> 1) <= t) ++tI;
  const int tJ = tI + (t - ((65 * tI - tI * tI) >> 1));
  const int I0 = tI * 8, J0 = tJ * 8;
  const int rowB = b * 256;

  const int lane = tid & 63;
  const int wn2 = tid >> 6;
  const int col = lane & 15, quad = lane >> 4;

  // ---- B-fragments to registers (32 VGPR), L2-broadcast, held through MFMA ----
  const int uB = ((wn2 & 1) << 1) | (wn2 >> 1);
  uint4 gB[8];
#pragma unroll
  for (int ks = 0; ks < 8; ++ks)
    gB[ks] = reinterpret_cast<const uint4*>(W1f8)[(ks * 4 + uB) * 64 + lane];

  // ---- stage sPP: 16 rows x 128 u32 {PiB'|Pjf'} bf16-packed, coalesced ----
#pragma unroll
  for (int it = 0; it < 2; ++it) {
    int fidx = it * 256 + tid;  // 512 float4 slots
    int row = fidx >> 5, d4 = fidx & 31;
    int gr = rowB + ((row < 8) ? (I0 + row) : (J0 + row - 8));
    float4 a = reinterpret_cast<const float4*>(PiB + (size_t)gr * 128)[d4];
    float4 c = reinterpret_cast<const float4*>(Pjf + (size_t)gr * 128)[d4];
    uint4 u;
    u.x = pkbf2(a.x, c.x);
    u.y = pkbf2(a.y, c.y);
    u.z = pkbf2(a.z, c.z);
    u.w = pkbf2(a.w, c.w);
    *reinterpret_cast<uint4*>(&sPP[row * 132 + d4 * 4]) = u;
  }

  // ---- stage scal (x256) fp32: fwd (tid<64) and mirror (tid in [64,128)) ----
  if (tid < 128) {
    int p = tid & 63, dir = tid >> 6;
    int iN = I0 + (p >> 3), jN = J0 + (p & 7);
    int rr = dir ? jN : iN, cc = dir ? iN : jN;
    float bl = fminf(fmaxf(baseL[(size_t)(rowB + rr) * 256 + cc], -20.f), 20.f);
    float cl = fminf(fmaxf(compL[(size_t)(rowB + rr) * 256 + cc], -20.f), 20.f);
    float4 v;
    v.x = 256.f * bl;
    v.y = 256.f / (1.f + __expf(-bl));
    v.z = 256.f * cl;
    v.w = 256.f / (1.f + __expf(-cl));
    *reinterpret_cast<float4*>(&sScal[p * 12 + dir * 4]) = v;
  }

  // ---- per-lane epilogue constants (2 ni columns) ----
  float cB0[2], cB1[2], cB2[2], cB3[2], cW2[2];
#pragma unroll
  for (int ni = 0; ni < 2; ++ni) {
    int h = (wn2 * 2 + ni) * 16 + col;
    cB0[ni] = W1[512 * 128 + h];
    cB1[ni] = W1[513 * 128 + h];
    cB2[ni] = W1[514 * 128 + h];
    cB3[ni] = W1[515 * 128 + h];
    cW2[ni] = W2[h] * INV256;
  }
  const float b2v = b2[0];

  // ---- F-build: 64 pairs x 256 k fp8, node direct from global (L1/L2-hot) ----
  {
    const int d4 = tid & 31;
    const int rr = tid >> 5;  // j-row 0..7
    const int ks1 = d4 >> 3, qd = (d4 >> 1) & 3, kb = (d4 & 1) * 4;
    const int scolbase = 2 * qd + 4 * ks1;
    const float4 hj = *reinterpret_cast<const float4*>(node + (size_t)(rowB + J0 + rr) * 128 + d4 * 4);
#pragma unroll
    for (int ii = 0; ii < 8; ++ii) {
      const float4 hi = *reinterpret_cast<const float4*>(node + (size_t)(rowB + I0 + ii) * 128 + d4 * 4);
      uint32_t du = pk4(fabsf(hi.x - hj.x), fabsf(hi.y - hj.y),
                        fabsf(hi.z - hj.z), fabsf(hi.w - hj.w));
      uint32_t pu = pk4(hi.x * hj.x, hi.y * hj.y, hi.z * hj.z, hi.w * hj.w);
      int p = ii * 8 + rr;
      int colp = p & 15, mi = p >> 4;
      int scol = (colp + scolbase) & 15;
      uint32_t addr = mi * 512 + qd * 128 + scol * 8 + kb;
      *reinterpret_cast<uint32_t*>(sF + ks1 * 2048 + addr) = du;
      *reinterpret_cast<uint32_t*>(sF + (ks1 + 4) * 2048 + addr) = pu;
    }
  }
  __syncthreads();

  // ---- MFMA: acc[4 mi][2 ni], K=256; A from swizzled LDS, B from registers ----
  f32x4 acc[4][2] = {};
#pragma unroll
  for (int ks = 0; ks < 8; ++ks) {
    long bb0 = mk64(gB[ks].x, gB[ks].y);
    long bb1 = mk64(gB[ks].z, gB[ks].w);
    const int ascol = (col + 2 * quad + 4 * (ks & 3)) & 15;
    const char* aks = sF + ks * 2048 + quad * 128 + ascol * 8;
#pragma unroll
    for (int mi = 0; mi < 4; ++mi) {
      uint2 av = *reinterpret_cast<const uint2*>(aks + mi * 512);
      long aa = mk64(av.x, av.y);
      acc[mi][0] = __builtin_amdgcn_mfma_f32_16x16x32_fp8_fp8(aa, bb0, acc[mi][0], 0, 0, 0);
      acc[mi][1] = __builtin_amdgcn_mfma_f32_16x16x32_fp8_fp8(aa, bb1, acc[mi][1], 0, 0, 0);
    }
  }
  __syncthreads();  // sF reads done -> sP overlay writable

  // ---- epilogue: fwd+mirror, DPP quad reduction, 16 partials/pair ----
  uint32_t uJ[4][2];
#pragma unroll
  for (int r = 0; r < 4; ++r)
#pragma unroll
    for (int ni = 0; ni < 2; ++ni)
      uJ[r][ni] = sPP[(8 + (quad & 1) * 4 + r) * 132 + (wn2 * 2 + ni) * 16 + col];

#pragma unroll
  for (int mi = 0; mi < 4; ++mi) {
    const int ii = mi * 2 + (quad >> 1);
    uint32_t uI[2];
#pragma unroll
    for (int ni = 0; ni < 2; ++ni)
      uI[ni] = sPP[ii * 132 + (wn2 * 2 + ni) * 16 + col];
#pragma unroll
    for (int r = 0; r < 4; ++r) {
      int p = mi * 16 + quad * 4 + r;  // C/D: pair row = quad*4 + r
      float4 scf = *reinterpret_cast<const float4*>(&sScal[p * 12]);
      float4 scm = *reinterpret_cast<const float4*>(&sScal[p * 12 + 4]);
      float vf = 0.f, vm = 0.f;
#pragma unroll
      for (int ni = 0; ni < 2; ++ni) {
        float piI = ulo(uI[ni]), pjI = uhi(uI[ni]);
        float piJ = ulo(uJ[r][ni]), pjJ = uhi(uJ[r][ni]);
        float a = acc[mi][ni][r];
        float pf = (a + piI) + pjJ;
        pf = fmaf(scf.x, cB0[ni], pf);
        pf = fmaf(scf.y, cB1[ni], pf);
        pf = fmaf(scf.z, cB2[ni], pf);
        pf = fmaf(scf.w, cB3[ni], pf);
        float pm = (a + piJ) + pjI;
        pm = fmaf(scm.x, cB0[ni], pm);
        pm = fmaf(scm.y, cB1[ni], pm);
        pm = fmaf(scm.z, cB2[ni], pm);
        pm = fmaf(scm.w, cB3[ni], pm);
        vf = fmaf(fmaxf(pf, 0.f), cW2[ni], vf);
        vm = fmaf(fmaxf(pm, 0.f), cW2[ni], vm);
      }
      vf = qsum4(vf);
      vm = qsum4(vm);
      if ((col & 3) == 0) {
        int part = wn2 * 4 + (col >> 2);
        sP[p * 42 + part] = vf;
        sP[p * 42 + 20 + part] = vm;
      }
    }
  }
  __syncthreads();

  // ---- final: sum 16 fwd + 16 mirror partials, symmetric store ----
  if (tid < 64) {
    int p = tid;
    const float2* f2 = reinterpret_cast<const float2*>(sP + p * 42);
    const float2* m2 = reinterpret_cast<const float2*>(sP + p * 42 + 20);
    float sumF = 0.f, sumM = 0.f;
#pragma unroll
    for (int c = 0; c < 8; ++c) {
      float2 a = f2[c], d = m2[c];
      sumF += a.x + a.y;
      sumM += d.x + d.y;
    }
    float val = 0.5f * (sumF + sumM) + b2v;
    int iN = I0 + (p >> 3), jN = J0 + (p & 7);
    if (iN == jN) val = -1e9f;
    out[(size_t)(rowB + iN) * 256 + jN] = val;
    out[(size_t)(rowB + jN) * 256 + iN] = val;
  }
}

extern "C" void kernel_launch(void* const* d_in, const int* in_sizes, int n_in,
                              void* d_out, int out_size, void* d_ws, size_t ws_size,
                              hipStream_t stream) {
  const float* node = (const float*)d_in[0];   // [4,256,128]
  const float* baseL = (const float*)d_in[1];  // [4,256,256]
  const float* compL = (const float*)d_in[2];  // [4,256,256]
  const float* W1 = (const float*)d_in[3];     // [516,128]
  const float* b1 = (const float*)d_in[4];     // [128]
  const float* W2 = (const float*)d_in[5];     // [128,1]
  const float* b2 = (const float*)d_in[6];     // [1]
  float* out = (float*)d_out;                  // [4,256,256] fp32

  char* ws = (char*)d_ws;
  float* PiB = (float*)(ws);                        // 512 KB
  float* Pjf = (float*)(ws + (512 << 10));          // 512 KB
  uint32_t* W1f8 = (uint32_t*)(ws + (1024 << 10));  // 32 KB

  pre_k<<<288, 256, 0, stream>>>(node, W1, b1, PiB, Pjf, W1f8);
  main_k<<<2112, 256, 0, stream>>>(node, baseL, compL, W1, W2, b2, W1f8, PiB, Pjf, out);
}